// Round 1
// baseline (73.402 us; speedup 1.0000x reference)
//
#include <hip/hip_runtime.h>

#define BNEPS 1e-5f

// ---------------------------------------------------------------------------
// The reference network's output is batch-constant (see analysis): binarize
// after relu is identically +1, so the fire module's outputs do not depend on
// the input x at all. We compute logits L[1000] and feat F[128] once, then
// broadcast them over all 8192 rows.
// ---------------------------------------------------------------------------

// ws layout (floats): [0..1000) = L (logits row), [1024..1152) = F (feat row)

__global__ __launch_bounds__(256) void compute_consts(
    const float* __restrict__ w_e1, const float* __restrict__ b_e1,
    const float* __restrict__ w_pw,
    const float* __restrict__ bnpw_g, const float* __restrict__ bnpw_b,
    const float* __restrict__ bnpw_m, const float* __restrict__ bnpw_v,
    const float* __restrict__ bnf_g, const float* __restrict__ bnf_b,
    const float* __restrict__ bnf_m, const float* __restrict__ bnf_v,
    const float* __restrict__ w1, const float* __restrict__ b1,
    const float* __restrict__ bnc_g, const float* __restrict__ bnc_b,
    const float* __restrict__ bnc_m, const float* __restrict__ bnc_v,
    const float* __restrict__ w2, const float* __restrict__ b2,
    float* __restrict__ ws)
{
    __shared__ __align__(16) float e1c[128];
    __shared__ __align__(16) float e3c[128];
    __shared__ __align__(16) float hb[2304];
    __shared__ __align__(16) float Cc[128];

    const int tid = threadIdx.x;

    // expand1x1: all-ones binarized input -> row-sum of sign(w_e1) + bias, relu
    // expand3x3 (pw after dead dw branch): sign-sum of w_pw -> bn -> relu
    if (tid < 128) {
        float s = 0.f;
        #pragma unroll
        for (int c = 0; c < 32; ++c)
            s += (w_e1[tid * 32 + c] >= 0.f) ? 1.f : -1.f;
        s += b_e1[tid];
        e1c[tid] = fmaxf(s, 0.f);

        float p = 0.f;
        #pragma unroll
        for (int c = 0; c < 32; ++c)
            p += (w_pw[tid * 32 + c] >= 0.f) ? 1.f : -1.f;
        float inv = bnpw_g[tid] * rsqrtf(bnpw_v[tid] + BNEPS);
        e3c[tid] = fmaxf((p - bnpw_m[tid]) * inv + bnpw_b[tid], 0.f);
    }
    __syncthreads();

    // flattened [256,3,3] -> 2304 features, then BN1d(2304)
    for (int f = tid; f < 2304; f += 256) {
        int ch = f / 9;
        float v = (ch < 128) ? e1c[ch] : e3c[ch - 128];
        float inv = bnf_g[f] * rsqrtf(bnf_v[f] + BNEPS);
        hb[f] = (v - bnf_m[f]) * inv + bnf_b[f];
    }
    __syncthreads();

    // feat = hb @ w1.T + b1   (128 outputs, K=2304)
    if (tid < 128) {
        const float4* w1r = reinterpret_cast<const float4*>(w1 + tid * 2304);
        const float4* hb4 = reinterpret_cast<const float4*>(hb);
        float ax = 0.f, ay = 0.f, az = 0.f, aw = 0.f;
        for (int f4 = 0; f4 < 576; ++f4) {
            float4 w = w1r[f4];
            float4 h = hb4[f4];
            ax += w.x * h.x; ay += w.y * h.y; az += w.z * h.z; aw += w.w * h.w;
        }
        float F = (ax + ay) + (az + aw) + b1[tid];
        ws[1024 + tid] = F;
        float r = fmaxf(F, 0.f);
        float inv = bnc_g[tid] * rsqrtf(bnc_v[tid] + BNEPS);
        Cc[tid] = (r - bnc_m[tid]) * inv + bnc_b[tid];
    }
    __syncthreads();

    // logits = Cc @ w2.T + b2   (1000 outputs, K=128)
    const float4* Cc4 = reinterpret_cast<const float4*>(Cc);
    for (int n = tid; n < 1000; n += 256) {
        const float4* w2r = reinterpret_cast<const float4*>(w2 + n * 128);
        float ax = 0.f, ay = 0.f, az = 0.f, aw = 0.f;
        #pragma unroll
        for (int o4 = 0; o4 < 32; ++o4) {
            float4 w = w2r[o4];
            float4 c = Cc4[o4];
            ax += w.x * c.x; ay += w.y * c.y; az += w.z * c.z; aw += w.w * c.w;
        }
        ws[n] = (ax + ay) + (az + aw) + b2[n];
    }
}

// Broadcast: out[0 .. 8192*1000) = L tiled per row; out[.. +8192*128) = F tiled.
__global__ __launch_bounds__(256) void broadcast_out(
    const float* __restrict__ ws, float* __restrict__ out)
{
    __shared__ __align__(16) float sL[1000];
    __shared__ __align__(16) float sF[128];
    const int tid = threadIdx.x;
    for (int i = tid; i < 1000; i += 256) sL[i] = ws[i];
    if (tid < 128) sF[tid] = ws[1024 + tid];
    __syncthreads();

    const float4* sL4 = reinterpret_cast<const float4*>(sL);
    const float4* sF4 = reinterpret_cast<const float4*>(sF);
    float4* out4 = reinterpret_cast<float4*>(out);

    const int TOT = 2310144;   // 9,240,576 floats / 4
    const int LOG = 2048000;   // 8,192,000 floats / 4 (logits section)

    for (int i = blockIdx.x * blockDim.x + tid; i < TOT;
         i += gridDim.x * blockDim.x) {
        float4 v;
        if (i < LOG) {
            v = sL4[i % 250];          // 1000 floats = 250 float4 per row
        } else {
            v = sF4[(i - LOG) & 31];   // 128 floats = 32 float4 per row
        }
        out4[i] = v;
    }
}

extern "C" void kernel_launch(void* const* d_in, const int* in_sizes, int n_in,
                              void* d_out, int out_size, void* d_ws, size_t ws_size,
                              hipStream_t stream) {
    (void)in_sizes; (void)n_in; (void)out_size; (void)ws_size;

    const float* w_e1  = (const float*)d_in[7];
    const float* b_e1  = (const float*)d_in[8];
    const float* w_pw  = (const float*)d_in[14];
    const float* bnpw_g = (const float*)d_in[15];
    const float* bnpw_b = (const float*)d_in[16];
    const float* bnpw_m = (const float*)d_in[17];
    const float* bnpw_v = (const float*)d_in[18];
    const float* bnf_g = (const float*)d_in[19];
    const float* bnf_b = (const float*)d_in[20];
    const float* bnf_m = (const float*)d_in[21];
    const float* bnf_v = (const float*)d_in[22];
    const float* w1    = (const float*)d_in[23];
    const float* b1    = (const float*)d_in[24];
    const float* bnc_g = (const float*)d_in[25];
    const float* bnc_b = (const float*)d_in[26];
    const float* bnc_m = (const float*)d_in[27];
    const float* bnc_v = (const float*)d_in[28];
    const float* w2    = (const float*)d_in[29];
    const float* b2    = (const float*)d_in[30];

    float* ws  = (float*)d_ws;
    float* out = (float*)d_out;

    hipLaunchKernelGGL(compute_consts, dim3(1), dim3(256), 0, stream,
                       w_e1, b_e1, w_pw,
                       bnpw_g, bnpw_b, bnpw_m, bnpw_v,
                       bnf_g, bnf_b, bnf_m, bnf_v,
                       w1, b1,
                       bnc_g, bnc_b, bnc_m, bnc_v,
                       w2, b2, ws);

    hipLaunchKernelGGL(broadcast_out, dim3(2048), dim3(256), 0, stream, ws, out);
}

// Round 2
// 24.244 us; speedup vs baseline: 3.0276x; 3.0276x over previous
//
#include <hip/hip_runtime.h>

#define BNEPS 1e-5f

// ---------------------------------------------------------------------------
// The reference network's output is batch-constant: binarize(relu(x)) == +1
// everywhere, so the fire module's outputs are data-independent. We compute
// feat F[128] and logits L[1000] once, then broadcast over the 8192 rows.
//
// ws layout (floats): [0..1000) = L, [1024..1152) = F, [1152..1280) = Cc
// ---------------------------------------------------------------------------

// One block per feat output o. Each block redundantly recomputes hb[2304]
// (cheap, L2-resident after first block) then reduces hb . w1[o].
__global__ __launch_bounds__(256) void feat_kernel(
    const float* __restrict__ w_e1, const float* __restrict__ b_e1,
    const float* __restrict__ w_pw,
    const float* __restrict__ bnpw_g, const float* __restrict__ bnpw_b,
    const float* __restrict__ bnpw_m, const float* __restrict__ bnpw_v,
    const float* __restrict__ bnf_g, const float* __restrict__ bnf_b,
    const float* __restrict__ bnf_m, const float* __restrict__ bnf_v,
    const float* __restrict__ w1, const float* __restrict__ b1,
    const float* __restrict__ bnc_g, const float* __restrict__ bnc_b,
    const float* __restrict__ bnc_m, const float* __restrict__ bnc_v,
    float* __restrict__ ws)
{
    __shared__ __align__(16) float e1c[128];
    __shared__ __align__(16) float e3c[128];
    __shared__ __align__(16) float hb[2304];
    __shared__ float red[4];

    const int tid = threadIdx.x;
    const int o = blockIdx.x;          // 0..127

    // channel constants after squeeze (binarized inputs are all +1)
    if (tid < 128) {
        float s = 0.f;
        #pragma unroll
        for (int c = 0; c < 32; ++c)
            s += (w_e1[tid * 32 + c] >= 0.f) ? 1.f : -1.f;
        e1c[tid] = fmaxf(s + b_e1[tid], 0.f);

        float p = 0.f;
        #pragma unroll
        for (int c = 0; c < 32; ++c)
            p += (w_pw[tid * 32 + c] >= 0.f) ? 1.f : -1.f;
        float inv = bnpw_g[tid] * rsqrtf(bnpw_v[tid] + BNEPS);
        e3c[tid] = fmaxf((p - bnpw_m[tid]) * inv + bnpw_b[tid], 0.f);
    }
    __syncthreads();

    // hb = BN1d_2304(flatten(concat(e1,e3)))
    for (int f = tid; f < 2304; f += 256) {
        int ch = f / 9;
        float v = (ch < 128) ? e1c[ch] : e3c[ch - 128];
        float inv = bnf_g[f] * rsqrtf(bnf_v[f] + BNEPS);
        hb[f] = (v - bnf_m[f]) * inv + bnf_b[f];
    }
    __syncthreads();

    // F[o] = hb . w1[o] + b1[o], coalesced across the block
    const float4* __restrict__ w1r = reinterpret_cast<const float4*>(w1 + o * 2304);
    const float4* __restrict__ hb4 = reinterpret_cast<const float4*>(hb);
    float acc = 0.f;
    for (int j = tid; j < 576; j += 256) {
        float4 w = w1r[j];
        float4 h = hb4[j];
        acc += w.x * h.x + w.y * h.y + w.z * h.z + w.w * h.w;
    }
    #pragma unroll
    for (int off = 32; off > 0; off >>= 1)
        acc += __shfl_down(acc, off);

    const int lane = tid & 63, wave = tid >> 6;
    if (lane == 0) red[wave] = acc;
    __syncthreads();
    if (tid == 0) {
        float F = (red[0] + red[1]) + (red[2] + red[3]) + b1[o];
        ws[1024 + o] = F;
        float r = fmaxf(F, 0.f);
        float inv = bnc_g[o] * rsqrtf(bnc_v[o] + BNEPS);
        ws[1152 + o] = (r - bnc_m[o]) * inv + bnc_b[o];
    }
}

// One wave per logit: L[n] = Cc . w2[n] + b2[n]
__global__ __launch_bounds__(256) void logits_kernel(
    const float* __restrict__ w2, const float* __restrict__ b2,
    float* __restrict__ ws)
{
    __shared__ __align__(16) float sC[128];
    const int tid = threadIdx.x;
    if (tid < 128) sC[tid] = ws[1152 + tid];
    __syncthreads();

    const int lane = tid & 63, wave = tid >> 6;
    const int n = blockIdx.x * 4 + wave;   // grid 250 * 4 waves = 1000
    const float2* __restrict__ w2r = reinterpret_cast<const float2*>(w2 + n * 128);
    float2 w = w2r[lane];
    float acc = w.x * sC[2 * lane] + w.y * sC[2 * lane + 1];
    #pragma unroll
    for (int off = 32; off > 0; off >>= 1)
        acc += __shfl_down(acc, off);
    if (lane == 0) ws[n] = acc + b2[n];
}

// Broadcast: out[0 .. 8192*1000) = L per row; then 8192*128 of F per row.
__global__ __launch_bounds__(256) void broadcast_out(
    const float* __restrict__ ws, float* __restrict__ out)
{
    __shared__ __align__(16) float sL[1000];
    __shared__ __align__(16) float sF[128];
    const int tid = threadIdx.x;
    for (int i = tid; i < 1000; i += 256) sL[i] = ws[i];
    if (tid < 128) sF[tid] = ws[1024 + tid];
    __syncthreads();

    const float4* sL4 = reinterpret_cast<const float4*>(sL);
    const float4* sF4 = reinterpret_cast<const float4*>(sF);
    float4* out4 = reinterpret_cast<float4*>(out);

    const int TOT = 2310144;   // 9,240,576 floats / 4
    const int LOG = 2048000;   // 8,192,000 floats / 4 (logits section)

    for (int i = blockIdx.x * blockDim.x + tid; i < TOT;
         i += gridDim.x * blockDim.x) {
        float4 v;
        if (i < LOG) {
            v = sL4[i % 250];          // 1000 floats = 250 float4 per row
        } else {
            v = sF4[(i - LOG) & 31];   // 128 floats = 32 float4 per row
        }
        out4[i] = v;
    }
}

extern "C" void kernel_launch(void* const* d_in, const int* in_sizes, int n_in,
                              void* d_out, int out_size, void* d_ws, size_t ws_size,
                              hipStream_t stream) {
    (void)in_sizes; (void)n_in; (void)out_size; (void)ws_size;

    const float* w_e1  = (const float*)d_in[7];
    const float* b_e1  = (const float*)d_in[8];
    const float* w_pw  = (const float*)d_in[14];
    const float* bnpw_g = (const float*)d_in[15];
    const float* bnpw_b = (const float*)d_in[16];
    const float* bnpw_m = (const float*)d_in[17];
    const float* bnpw_v = (const float*)d_in[18];
    const float* bnf_g = (const float*)d_in[19];
    const float* bnf_b = (const float*)d_in[20];
    const float* bnf_m = (const float*)d_in[21];
    const float* bnf_v = (const float*)d_in[22];
    const float* w1    = (const float*)d_in[23];
    const float* b1    = (const float*)d_in[24];
    const float* bnc_g = (const float*)d_in[25];
    const float* bnc_b = (const float*)d_in[26];
    const float* bnc_m = (const float*)d_in[27];
    const float* bnc_v = (const float*)d_in[28];
    const float* w2    = (const float*)d_in[29];
    const float* b2    = (const float*)d_in[30];

    float* ws  = (float*)d_ws;
    float* out = (float*)d_out;

    hipLaunchKernelGGL(feat_kernel, dim3(128), dim3(256), 0, stream,
                       w_e1, b_e1, w_pw,
                       bnpw_g, bnpw_b, bnpw_m, bnpw_v,
                       bnf_g, bnf_b, bnf_m, bnf_v,
                       w1, b1,
                       bnc_g, bnc_b, bnc_m, bnc_v, ws);

    hipLaunchKernelGGL(logits_kernel, dim3(250), dim3(256), 0, stream,
                       w2, b2, ws);

    hipLaunchKernelGGL(broadcast_out, dim3(2048), dim3(256), 0, stream, ws, out);
}